// Round 5
// baseline (2272.378 us; speedup 1.0000x reference)
//
#include <hip/hip_runtime.h>
#include <math.h>

#define N_NODES    100000
#define K_NEIGH    32
#define OUT_STRIDE 448      // 3*128 + 64
#define NPASS      4
#define PRANGE     25000    // slab: 25000 rows * 128B = 3.2 MB < 4 MB per-XCD L2
#define ACC_GRID   1000     // co-resident: 4 blocks/CU * 256 CU = 1024 >= 1000
#define NW         25       // nodes per wave: 1000*4*25 = 100000 exactly
#define PREP_NPB   128      // prep nodes per block

typedef __attribute__((ext_vector_type(8))) __bf16 bf16x8;
typedef __attribute__((ext_vector_type(4))) float  f32x4;

// bf16 helpers (RNE)
static __device__ __forceinline__ unsigned short f2bf(float f) {
    unsigned int u = __float_as_uint(f);
    return (unsigned short)((u + 0x7FFFu + ((u >> 16) & 1u)) >> 16);
}
static __device__ __forceinline__ float bf2f(unsigned short h) {
    return __uint_as_float(((unsigned int)h) << 16);
}

// ---------------------------------------------------------------------------
// Prep: per-node FULL SORT of edges by neighbor index j (sum/max are
// permutation-invariant -> legal). Packed e = (j<<15) | w15; j in high bits
// so ascending sort == sort by j. acc processes positions [8p,8p+8) during
// pass p: ~81% of gathers hit the pass-p slab with a STATIC schedule.
// ---------------------------------------------------------------------------
__global__ __launch_bounds__(256) void prep_kernel(
    const float* __restrict__ dist, const int* __restrict__ idx,
    unsigned int* __restrict__ iwb,
    const float* __restrict__ W0, const float* __restrict__ W1,
    const float* __restrict__ W2,
    unsigned short* __restrict__ Wt0, unsigned short* __restrict__ Wt1,
    unsigned short* __restrict__ Wt2, unsigned int* __restrict__ bar)
{
    __shared__ unsigned int eLDS[PREP_NPB * 33];   // padded: bank-spread slices
    __shared__ float        dLDS[PREP_NPB * K_NEIGH];

    const int tid = threadIdx.x;
    const int gi  = blockIdx.x * 256 + tid;

    if (gi == 0) bar[0] = 0u;
    if (gi < 64 * 64)  Wt0[(gi & 63) * 64  + (gi >> 6)] = f2bf(W0[gi]);  // gi = k*64+n
    if (gi < 128 * 64) Wt1[(gi & 63) * 128 + (gi >> 6)] = f2bf(W1[gi]);
    if (gi < 128 * 64) Wt2[(gi & 63) * 128 + (gi >> 6)] = f2bf(W2[gi]);

    const int nb0 = blockIdx.x * PREP_NPB;
    for (int t = tid; t < PREP_NPB * K_NEIGH; t += 256) {
        if (nb0 + (t >> 5) < N_NODES) {
            const size_t g = (size_t)nb0 * K_NEIGH + t;
            eLDS[(t >> 5) * 33 + (t & 31)] = (unsigned int)idx[g];
            dLDS[t] = dist[g];
        }
    }
    __syncthreads();

    if (tid < PREP_NPB && nb0 + tid < N_NODES) {
        const int base = tid * 33;
        for (int k = 0; k < K_NEIGH; ++k) {
            const unsigned j = eLDS[base + k];
            const float w = __expf(-10.f * dLDS[tid * K_NEIGH + k]);
            const unsigned w15 = (unsigned)(w * 32767.f + 0.5f);
            eLDS[base + k] = (j << 15) | w15;
        }
        for (int k = 1; k < K_NEIGH; ++k) {           // insertion sort ascending
            const unsigned key = eLDS[base + k];
            int m = k - 1;
            while (m >= 0 && eLDS[base + m] > key) {
                eLDS[base + m + 1] = eLDS[base + m];
                --m;
            }
            eLDS[base + m + 1] = key;
        }
    }
    __syncthreads();

    for (int t = tid; t < PREP_NPB * K_NEIGH; t += 256) {
        if (nb0 + (t >> 5) < N_NODES)
            iwb[(size_t)nb0 * K_NEIGH + t] = eLDS[(t >> 5) * 33 + (t & 31)];
    }
}

// ---------------------------------------------------------------------------
// Dense layer via MFMA (unchanged; F row-major [n][64] bf16).
// ---------------------------------------------------------------------------
template <int DIN, bool COPY_X>
__global__ __launch_bounds__(256) void dense_kernel(
    const float* __restrict__ in, int in_stride,
    const unsigned short* __restrict__ Wt,   // [64][DIN] bf16 (transposed W)
    const float* __restrict__ b,
    unsigned short* __restrict__ F, float* __restrict__ out)
{
    constexpr int LDK = DIN + 8;
    __shared__ unsigned short aLDS[64 * LDK];
    __shared__ unsigned short bLDS[64 * LDK];

    const int tid  = threadIdx.x;
    const int row0 = blockIdx.x * 64;

    for (int i = tid; i < 64 * (DIN / 4); i += 256) {
        const int r = i / (DIN / 4);
        const int c = (i % (DIN / 4)) * 4;
        const int n = row0 + r;
        float4 v = make_float4(0.f, 0.f, 0.f, 0.f);
        if (n < N_NODES) {
            v = *(const float4*)&in[(size_t)n * in_stride + c];
            if (COPY_X) *(float4*)&out[(size_t)n * OUT_STRIDE + 384 + c] = v;
        }
        const unsigned int u0 = (unsigned int)f2bf(v.x) | ((unsigned int)f2bf(v.y) << 16);
        const unsigned int u1 = (unsigned int)f2bf(v.z) | ((unsigned int)f2bf(v.w) << 16);
        *(uint2*)&aLDS[r * LDK + c] = make_uint2(u0, u1);
    }
    for (int i = tid; i < 64 * (DIN / 8); i += 256) {
        const int nn = i / (DIN / 8);
        const int k0 = (i % (DIN / 8)) * 8;
        *(uint4*)&bLDS[nn * LDK + k0] = *(const uint4*)&Wt[nn * DIN + k0];
    }
    __syncthreads();

    const int lane = tid & 63;
    const int wv   = tid >> 6;
    const int m    = lane & 15;
    const int quad = lane >> 4;

    f32x4 acc[4];
#pragma unroll
    for (int nb = 0; nb < 4; ++nb) acc[nb] = (f32x4){0.f, 0.f, 0.f, 0.f};

#pragma unroll
    for (int ks = 0; ks < DIN / 32; ++ks) {
        const int koff = ks * 32 + quad * 8;
        const bf16x8 afr =
            *reinterpret_cast<const bf16x8*>(&aLDS[(wv * 16 + m) * LDK + koff]);
#pragma unroll
        for (int nb = 0; nb < 4; ++nb) {
            const bf16x8 bfr =
                *reinterpret_cast<const bf16x8*>(&bLDS[(nb * 16 + m) * LDK + koff]);
            acc[nb] = __builtin_amdgcn_mfma_f32_16x16x32_bf16(afr, bfr, acc[nb], 0, 0, 0);
        }
    }

#pragma unroll
    for (int nb = 0; nb < 4; ++nb) {
        const int c    = nb * 16 + m;
        const float bc = b[c];
#pragma unroll
        for (int reg = 0; reg < 4; ++reg) {
            const int n = row0 + wv * 16 + quad * 4 + reg;
            if (n < N_NODES) {
                const float vv = fmaxf(acc[nb][reg] + bc, 0.f);
                F[(size_t)n * 64 + c] = f2bf(vv);
            }
        }
    }
}

// ---------------------------------------------------------------------------
// KNN accumulate v6: pass-phased residency (v5, proven: FETCH 63MB) +
// v1's scalar-edge gather engine (proven: MLP ~20).
//   Edges read via WAVE-UNIFORM loads -> s_load through the scalar cache;
//   (j,w) decoded on the SALU; gather = global_load_ushort with SGPR-pair
//   row base + shared lane-offset VGPR -> in-flight cost = 1 VGPR/gather.
//   NO LDS, NO flat 64-bit VGPR address pairs, NO lgkmcnt in the gather path.
//   8 independent gathers per node x unrolled 25-node loop -> scheduler can
//   hold ~16-30 outstanding within the 128-VGPR budget (50 acc VGPRs).
//   Barrier: 1000 blocks co-resident (no LDS, VGPR<=128 => >=4 blocks/CU);
//   s_sleep(32) poll, bounded spins (degrade, never hang).
// ---------------------------------------------------------------------------
__global__ __launch_bounds__(256, 4) void acc_kernel(
    const unsigned short* __restrict__ F,
    const unsigned int* __restrict__ iwb,   // [N][32] sorted (j<<15)|w15
    float* __restrict__ out,                // already offset to layer slab
    unsigned int* __restrict__ bar)
{
    const int tid  = threadIdx.x;
    const int lane = tid & 63;
    const int wid  = __builtin_amdgcn_readfirstlane(blockIdx.x * 4 + (tid >> 6));
    const int n0   = wid * NW;

    const unsigned int* __restrict__ erow = iwb + (size_t)n0 * K_NEIGH; // uniform

    float sum[NW], mx[NW];
#pragma unroll
    for (int i = 0; i < NW; ++i) { sum[i] = 0.f; mx[i] = -INFINITY; }

    for (int p = 0; p < NPASS; ++p) {
#pragma unroll
        for (int i = 0; i < NW; ++i) {
            const unsigned int* __restrict__ ep = erow + i * K_NEIGH + p * 8;
            float g[8], wk[8];
#pragma unroll
            for (int t = 0; t < 8; ++t) {
                const unsigned e = ep[t];                  // uniform -> s_load (K$)
                wk[t] = (float)(e & 0x7FFFu) * (1.f / 32767.f);
                // SGPR row base + shared lane VGPR offset -> 1 VGPR in flight
                g[t]  = bf2f(F[(size_t)(e >> 15) * 64 + lane]);
            }
#pragma unroll
            for (int t = 0; t < 8; ++t) {
                const float v = wk[t] * g[t];
                sum[i] += v;
                mx[i]  = fmaxf(mx[i], v);
            }
        }
        if (p < NPASS - 1) {
            __syncthreads();
            if (tid == 0) {
                const unsigned tk = __hip_atomic_fetch_add(
                    bar, 1u, __ATOMIC_ACQ_REL, __HIP_MEMORY_SCOPE_AGENT);
                const unsigned target = (tk / ACC_GRID + 1u) * ACC_GRID;
                int spins = 0;
                while (__hip_atomic_load(bar, __ATOMIC_ACQUIRE,
                                         __HIP_MEMORY_SCOPE_AGENT) < target) {
                    __builtin_amdgcn_s_sleep(32);     // ~853ns poll: low contention
                    if (++spins > 8000) break;        // failsafe: degrade, never hang
                }
            }
            __syncthreads();
        }
    }

    // Epilogue: prev rows sequential per wave -> coalesced streaming reads.
#pragma unroll
    for (int i = 0; i < NW; ++i) {
        const int n = n0 + i;
        const float prev = bf2f(F[(size_t)n * 64 + lane]);
        float* orow = out + (size_t)n * OUT_STRIDE + lane;
        __builtin_nontemporal_store(sum[i] * (1.f / 32.f) - prev, orow);
        __builtin_nontemporal_store(mx[i] - prev, orow + 64);
    }
}

// ---------------------------------------------------------------------------
extern "C" void kernel_launch(void* const* d_in, const int* in_sizes, int n_in,
                              void* d_out, int out_size, void* d_ws, size_t ws_size,
                              hipStream_t stream)
{
    const float* x    = (const float*)d_in[0];
    const int*   idx  = (const int*)  d_in[1];
    const float* dist = (const float*)d_in[2];
    const float* W0   = (const float*)d_in[3];
    const float* b0   = (const float*)d_in[4];
    const float* W1   = (const float*)d_in[5];
    const float* b1   = (const float*)d_in[6];
    const float* W2   = (const float*)d_in[7];
    const float* b2   = (const float*)d_in[8];

    float* out = (float*)d_out;

    // Workspace layout (all 16B-aligned):
    char* ws = (char*)d_ws;
    unsigned short* F    = (unsigned short*)(ws);                 // 12.8 MB
    unsigned int*   iwb  = (unsigned int*)  (ws + 12800000);      // 12.8 MB
    unsigned short* Wt0  = (unsigned short*)(ws + 25600000);      // 8 KB
    unsigned short* Wt1  = (unsigned short*)(ws + 25608192);      // 16 KB
    unsigned short* Wt2  = (unsigned short*)(ws + 25624576);      // 16 KB
    unsigned int*   bar  = (unsigned int*)  (ws + 25640960);      // 4 B

    const int prep_grid  = (N_NODES + PREP_NPB - 1) / PREP_NPB;  // 782
    const int dense_grid = (N_NODES + 63) / 64;                  // 1563

    prep_kernel<<<prep_grid, 256, 0, stream>>>(dist, idx, iwb,
                                               W0, W1, W2, Wt0, Wt1, Wt2, bar);

    // Layer 0: dense from x (also copies x into out[:,384:448])
    dense_kernel<64, true><<<dense_grid, 256, 0, stream>>>(x, 64, Wt0, b0, F, out);
    acc_kernel<<<ACC_GRID, 256, 0, stream>>>(F, iwb, out + 0, bar);

    // Layer 1: dense reads layer-0 slab of out (it IS the next input)
    dense_kernel<128, false><<<dense_grid, 256, 0, stream>>>(out + 0, OUT_STRIDE, Wt1, b1, F, nullptr);
    acc_kernel<<<ACC_GRID, 256, 0, stream>>>(F, iwb, out + 128, bar);

    // Layer 2
    dense_kernel<128, false><<<dense_grid, 256, 0, stream>>>(out + 128, OUT_STRIDE, Wt2, b2, F, nullptr);
    acc_kernel<<<ACC_GRID, 256, 0, stream>>>(F, iwb, out + 256, bar);
}

// Round 6
// 1580.736 us; speedup vs baseline: 1.4375x; 1.4375x over previous
//
#include <hip/hip_runtime.h>
#include <math.h>

#define N_NODES    100000
#define K_NEIGH    32
#define OUT_STRIDE 448      // 3*128 + 64
#define NPASS      4
#define PRANGE     25000    // slab: 25000 rows * 128B = 3.2 MB < 4 MB per-XCD L2
#define ACC_GRID   1000     // co-resident: 4 blocks/CU * 256 CU = 1024 >= 1000
#define NW         25       // nodes per wave: 1000*4*25 = 100000 exactly
#define PREP_NPB   128      // prep nodes per block

typedef __attribute__((ext_vector_type(8))) __bf16 bf16x8;
typedef __attribute__((ext_vector_type(4))) float  f32x4;

// bf16 helpers (RNE)
static __device__ __forceinline__ unsigned short f2bf(float f) {
    unsigned int u = __float_as_uint(f);
    return (unsigned short)((u + 0x7FFFu + ((u >> 16) & 1u)) >> 16);
}
static __device__ __forceinline__ float bf2f(unsigned short h) {
    return __uint_as_float(((unsigned int)h) << 16);
}

// ---------------------------------------------------------------------------
// Prep: per-node FULL SORT of edges by neighbor index j (sum/max are
// permutation-invariant -> legal). Sorted edges are emitted PRE-DECODED:
//   jb[n][k] = j*128  (u32 byte offset of F row)   -> s_load, no bit decode
//   wf[n][k] = w15/32767 (f32 weight)              -> s_load, feeds v_mul
// acc processes positions [8p,8p+8) during pass p: ~81% of gathers hit the
// pass-p slab with a fully static schedule.
// ---------------------------------------------------------------------------
__global__ __launch_bounds__(256) void prep_kernel(
    const float* __restrict__ dist, const int* __restrict__ idx,
    unsigned int* __restrict__ jb, float* __restrict__ wf,
    const float* __restrict__ W0, const float* __restrict__ W1,
    const float* __restrict__ W2,
    unsigned short* __restrict__ Wt0, unsigned short* __restrict__ Wt1,
    unsigned short* __restrict__ Wt2, unsigned int* __restrict__ bar)
{
    __shared__ unsigned int eLDS[PREP_NPB * 33];   // padded: bank-spread slices
    __shared__ float        dLDS[PREP_NPB * K_NEIGH];

    const int tid = threadIdx.x;
    const int gi  = blockIdx.x * 256 + tid;

    if (gi == 0) bar[0] = 0u;
    if (gi < 64 * 64)  Wt0[(gi & 63) * 64  + (gi >> 6)] = f2bf(W0[gi]);  // gi = k*64+n
    if (gi < 128 * 64) Wt1[(gi & 63) * 128 + (gi >> 6)] = f2bf(W1[gi]);
    if (gi < 128 * 64) Wt2[(gi & 63) * 128 + (gi >> 6)] = f2bf(W2[gi]);

    const int nb0 = blockIdx.x * PREP_NPB;
    for (int t = tid; t < PREP_NPB * K_NEIGH; t += 256) {
        if (nb0 + (t >> 5) < N_NODES) {
            const size_t g = (size_t)nb0 * K_NEIGH + t;
            eLDS[(t >> 5) * 33 + (t & 31)] = (unsigned int)idx[g];
            dLDS[t] = dist[g];
        }
    }
    __syncthreads();

    if (tid < PREP_NPB && nb0 + tid < N_NODES) {
        const int base = tid * 33;
        for (int k = 0; k < K_NEIGH; ++k) {           // pack (j<<15)|w15
            const unsigned j = eLDS[base + k];
            const float w = __expf(-10.f * dLDS[tid * K_NEIGH + k]);
            const unsigned w15 = (unsigned)(w * 32767.f + 0.5f);
            eLDS[base + k] = (j << 15) | w15;
        }
        for (int k = 1; k < K_NEIGH; ++k) {           // insertion sort ascending
            const unsigned key = eLDS[base + k];
            int m = k - 1;
            while (m >= 0 && eLDS[base + m] > key) {
                eLDS[base + m + 1] = eLDS[base + m];
                --m;
            }
            eLDS[base + m + 1] = key;
        }
    }
    __syncthreads();

    for (int t = tid; t < PREP_NPB * K_NEIGH; t += 256) {
        if (nb0 + (t >> 5) < N_NODES) {
            const unsigned e = eLDS[(t >> 5) * 33 + (t & 31)];
            const size_t g = (size_t)nb0 * K_NEIGH + t;
            jb[g] = (e >> 15) << 7;                               // j * 128
            wf[g] = (float)(e & 0x7FFFu) * (1.f / 32767.f);
        }
    }
}

// ---------------------------------------------------------------------------
// Dense layer via MFMA (unchanged; F row-major [n][64] bf16).
// ---------------------------------------------------------------------------
template <int DIN, bool COPY_X>
__global__ __launch_bounds__(256) void dense_kernel(
    const float* __restrict__ in, int in_stride,
    const unsigned short* __restrict__ Wt,   // [64][DIN] bf16 (transposed W)
    const float* __restrict__ b,
    unsigned short* __restrict__ F, float* __restrict__ out)
{
    constexpr int LDK = DIN + 8;
    __shared__ unsigned short aLDS[64 * LDK];
    __shared__ unsigned short bLDS[64 * LDK];

    const int tid  = threadIdx.x;
    const int row0 = blockIdx.x * 64;

    for (int i = tid; i < 64 * (DIN / 4); i += 256) {
        const int r = i / (DIN / 4);
        const int c = (i % (DIN / 4)) * 4;
        const int n = row0 + r;
        float4 v = make_float4(0.f, 0.f, 0.f, 0.f);
        if (n < N_NODES) {
            v = *(const float4*)&in[(size_t)n * in_stride + c];
            if (COPY_X) *(float4*)&out[(size_t)n * OUT_STRIDE + 384 + c] = v;
        }
        const unsigned int u0 = (unsigned int)f2bf(v.x) | ((unsigned int)f2bf(v.y) << 16);
        const unsigned int u1 = (unsigned int)f2bf(v.z) | ((unsigned int)f2bf(v.w) << 16);
        *(uint2*)&aLDS[r * LDK + c] = make_uint2(u0, u1);
    }
    for (int i = tid; i < 64 * (DIN / 8); i += 256) {
        const int nn = i / (DIN / 8);
        const int k0 = (i % (DIN / 8)) * 8;
        *(uint4*)&bLDS[nn * LDK + k0] = *(const uint4*)&Wt[nn * DIN + k0];
    }
    __syncthreads();

    const int lane = tid & 63;
    const int wv   = tid >> 6;
    const int m    = lane & 15;
    const int quad = lane >> 4;

    f32x4 acc[4];
#pragma unroll
    for (int nb = 0; nb < 4; ++nb) acc[nb] = (f32x4){0.f, 0.f, 0.f, 0.f};

#pragma unroll
    for (int ks = 0; ks < DIN / 32; ++ks) {
        const int koff = ks * 32 + quad * 8;
        const bf16x8 afr =
            *reinterpret_cast<const bf16x8*>(&aLDS[(wv * 16 + m) * LDK + koff]);
#pragma unroll
        for (int nb = 0; nb < 4; ++nb) {
            const bf16x8 bfr =
                *reinterpret_cast<const bf16x8*>(&bLDS[(nb * 16 + m) * LDK + koff]);
            acc[nb] = __builtin_amdgcn_mfma_f32_16x16x32_bf16(afr, bfr, acc[nb], 0, 0, 0);
        }
    }

#pragma unroll
    for (int nb = 0; nb < 4; ++nb) {
        const int c    = nb * 16 + m;
        const float bc = b[c];
#pragma unroll
        for (int reg = 0; reg < 4; ++reg) {
            const int n = row0 + wv * 16 + quad * 4 + reg;
            if (n < N_NODES) {
                const float vv = fmaxf(acc[nb][reg] + bc, 0.f);
                F[(size_t)n * 64 + c] = f2bf(vv);
            }
        }
    }
}

// ---------------------------------------------------------------------------
// KNN accumulate v7: phased residency (proven: FETCH 63MB) + spill-proof
// engine.
//   amdgpu_waves_per_eu(4,4): allocator targets EXACTLY 4 waves/EU -> 128
//   VGPR budget -> 50 accumulators + ~16-32 in-flight gathers fit in regs
//   (v6 failed because launch_bounds' min-only hint let LLVM squeeze to 64
//   VGPR and spill ~900MB/dispatch to scratch).
//   Edges pre-decoded (jb=row byte offset, wf=f32 weight), wave-uniform ->
//   s_load through K$; per edge: 1 v_add (SGPR base + lane2 voffset),
//   1 global_load_ushort (saddr=F), v_mul(s_wk)+v_add+v_max. 4 VALU+1 VMEM.
//   #pragma unroll 2 -> 16 independent gathers per body; compiler pipelines
//   adjacent bodies -> MLP ~24-32 (v1's proven engine shape).
//   Barrier: proven ticket barrier, s_sleep(32), bounded spin failsafe
//   (phasing is performance-only; breaking the spin stays correct).
// ---------------------------------------------------------------------------
__global__ __launch_bounds__(256)
__attribute__((amdgpu_waves_per_eu(4, 4)))
void acc_kernel(
    const unsigned short* __restrict__ F,
    const unsigned int* __restrict__ jb,   // [N][32] sorted j*128
    const float* __restrict__ wf,          // [N][32] sorted weights f32
    float* __restrict__ out,               // already offset to layer slab
    unsigned int* __restrict__ bar)
{
    const int tid  = threadIdx.x;
    const int lane = tid & 63;
    const int wid  = __builtin_amdgcn_readfirstlane(blockIdx.x * 4 + (tid >> 6));
    const int n0   = wid * NW;

    const unsigned int* __restrict__ jrow = jb + (size_t)n0 * K_NEIGH; // uniform
    const float*        __restrict__ wrow = wf + (size_t)n0 * K_NEIGH; // uniform
    const char*         __restrict__ Fb   = (const char*)F;
    const int lane2 = lane * 2;

    float sum[NW], mx[NW];
#pragma unroll
    for (int i = 0; i < NW; ++i) { sum[i] = 0.f; mx[i] = -INFINITY; }

    for (int p = 0; p < NPASS; ++p) {
#pragma unroll 2
        for (int i = 0; i < NW; ++i) {
            const unsigned int* __restrict__ jp = jrow + i * K_NEIGH + p * 8;
            const float*        __restrict__ wp = wrow + i * K_NEIGH + p * 8;
            float g[8];
#pragma unroll
            for (int t = 0; t < 8; ++t) {
                const unsigned off = jp[t] + (unsigned)lane2;   // s + v -> voffset
                g[t] = bf2f(*(const unsigned short*)(Fb + off));
            }
#pragma unroll
            for (int t = 0; t < 8; ++t) {
                const float v = wp[t] * g[t];                   // v_mul (SGPR src)
                sum[i] += v;
                mx[i]  = fmaxf(mx[i], v);
            }
        }
        if (p < NPASS - 1) {
            __syncthreads();
            if (tid == 0) {
                const unsigned tk = __hip_atomic_fetch_add(
                    bar, 1u, __ATOMIC_ACQ_REL, __HIP_MEMORY_SCOPE_AGENT);
                const unsigned target = (tk / ACC_GRID + 1u) * ACC_GRID;
                int spins = 0;
                while (__hip_atomic_load(bar, __ATOMIC_ACQUIRE,
                                         __HIP_MEMORY_SCOPE_AGENT) < target) {
                    __builtin_amdgcn_s_sleep(32);     // ~853ns poll: low contention
                    if (++spins > 3000) break;        // failsafe: degrade, never hang
                }
            }
            __syncthreads();
        }
    }

    // Epilogue: prev rows sequential per wave -> coalesced streaming reads.
#pragma unroll
    for (int i = 0; i < NW; ++i) {
        const int n = n0 + i;
        const float prev = bf2f(F[(size_t)n * 64 + lane]);
        float* orow = out + (size_t)n * OUT_STRIDE + lane;
        __builtin_nontemporal_store(sum[i] * (1.f / 32.f) - prev, orow);
        __builtin_nontemporal_store(mx[i] - prev, orow + 64);
    }
}

// ---------------------------------------------------------------------------
extern "C" void kernel_launch(void* const* d_in, const int* in_sizes, int n_in,
                              void* d_out, int out_size, void* d_ws, size_t ws_size,
                              hipStream_t stream)
{
    const float* x    = (const float*)d_in[0];
    const int*   idx  = (const int*)  d_in[1];
    const float* dist = (const float*)d_in[2];
    const float* W0   = (const float*)d_in[3];
    const float* b0   = (const float*)d_in[4];
    const float* W1   = (const float*)d_in[5];
    const float* b1   = (const float*)d_in[6];
    const float* W2   = (const float*)d_in[7];
    const float* b2   = (const float*)d_in[8];

    float* out = (float*)d_out;

    // Workspace layout (all 16B-aligned):
    char* ws = (char*)d_ws;
    unsigned short* F    = (unsigned short*)(ws);                 // 12.8 MB
    unsigned int*   jbuf = (unsigned int*)  (ws + 12800000);      // 12.8 MB
    float*          wbuf = (float*)         (ws + 25600000);      // 12.8 MB
    unsigned short* Wt0  = (unsigned short*)(ws + 38400000);      // 8 KB
    unsigned short* Wt1  = (unsigned short*)(ws + 38408192);      // 16 KB
    unsigned short* Wt2  = (unsigned short*)(ws + 38424576);      // 16 KB
    unsigned int*   bar  = (unsigned int*)  (ws + 38440960);      // 4 B

    const int prep_grid  = (N_NODES + PREP_NPB - 1) / PREP_NPB;  // 782
    const int dense_grid = (N_NODES + 63) / 64;                  // 1563

    prep_kernel<<<prep_grid, 256, 0, stream>>>(dist, idx, jbuf, wbuf,
                                               W0, W1, W2, Wt0, Wt1, Wt2, bar);

    // Layer 0: dense from x (also copies x into out[:,384:448])
    dense_kernel<64, true><<<dense_grid, 256, 0, stream>>>(x, 64, Wt0, b0, F, out);
    acc_kernel<<<ACC_GRID, 256, 0, stream>>>(F, jbuf, wbuf, out + 0, bar);

    // Layer 1: dense reads layer-0 slab of out (it IS the next input)
    dense_kernel<128, false><<<dense_grid, 256, 0, stream>>>(out + 0, OUT_STRIDE, Wt1, b1, F, nullptr);
    acc_kernel<<<ACC_GRID, 256, 0, stream>>>(F, jbuf, wbuf, out + 128, bar);

    // Layer 2
    dense_kernel<128, false><<<dense_grid, 256, 0, stream>>>(out + 128, OUT_STRIDE, Wt2, b2, F, nullptr);
    acc_kernel<<<ACC_GRID, 256, 0, stream>>>(F, jbuf, wbuf, out + 256, bar);
}